// Round 1
// baseline (116.823 us; speedup 1.0000x reference)
//
#include <hip/hip_runtime.h>

#define B_ 4
#define N_ 8192
#define D_ 128
#define K_ 32
#define BM 64
#define THREADS 512

typedef short short8 __attribute__((ext_vector_type(8)));
typedef float f32x4 __attribute__((ext_vector_type(4)));

__device__ __forceinline__ unsigned short f2bf(float f) {
  unsigned int u = __float_as_uint(f);
  u += 0x7FFFu + ((u >> 16) & 1u);   // round-to-nearest-even
  return (unsigned short)(u >> 16);
}
__device__ __forceinline__ float bf2f(unsigned short h) {
  return __uint_as_float(((unsigned int)h) << 16);
}

__global__ __launch_bounds__(256) void cvt_kernel(const float4* __restrict__ x,
                                                  ushort4* __restrict__ xh, int n4) {
  int i = blockIdx.x * blockDim.x + threadIdx.x;
  if (i < n4) {
    float4 v = x[i];
    ushort4 o;
    o.x = f2bf(v.x); o.y = f2bf(v.y); o.z = f2bf(v.z); o.w = f2bf(v.w);
    xh[i] = o;
  }
}

// Fused: gather+mean -> [64x256]x[256x128] bf16 MFMA GEMM -> GELU -> +x -> LayerNorm
template<bool USE_BF16>
__global__ __launch_bounds__(THREADS, 4) void fused_kernel(
    const float* __restrict__ x, const int* __restrict__ adj,
    const float* __restrict__ W, const float* __restrict__ bias,
    const float* __restrict__ gamma, const float* __restrict__ beta,
    const unsigned short* __restrict__ xh, float* __restrict__ out) {

  // bf16 [64 rows][256 feats], row stride 512B, XOR-swizzled: byte ^= (row&7)<<4
  __shared__ __align__(16) unsigned char in_tile[BM * 512];
  __shared__ __align__(16) float y_lds[BM][D_];
  __shared__ int adj_lds[BM * K_];

  const int t    = threadIdx.x;
  const int wave = t >> 6;
  const int lane = t & 63;
  const int l15  = lane & 15;
  const int kg   = lane >> 4;          // k-group 0..3

  const int  bidx = blockIdx.x >> 7;   // 128 blocks per batch
  const int  n0   = (blockIdx.x & 127) * BM;
  const long row0 = (long)bidx * N_ + n0;

  // ---- W fragments: wave w owns output cols [w*16, w*16+16), held in regs ----
  const int dl = (wave << 4) + l15;
  short8 bw[8];
  #pragma unroll
  for (int ks = 0; ks < 8; ++ks) {
    #pragma unroll
    for (int j = 0; j < 8; ++j) {
      int f = ks * 32 + kg * 8 + j;
      bw[ks][j] = (short)f2bf(W[f * D_ + dl]);
    }
  }

  // ---- stage adj tile (coalesced) ----
  #pragma unroll
  for (int i = 0; i < (BM * K_) / THREADS; ++i)
    adj_lds[t + i * THREADS] = adj[row0 * K_ + t + i * THREADS];

  // ---- stage x rows into feats 0..127 (bf16, swizzled) ----
  if constexpr (USE_BF16) {
    #pragma unroll
    for (int i = 0; i < 2; ++i) {
      int idx = t + i * THREADS;           // 1024 chunks of 8 bf16
      int row = idx >> 4;
      int cp  = (idx & 15) * 8;
      uint4 v = *reinterpret_cast<const uint4*>(xh + (row0 + row) * D_ + cp);
      *reinterpret_cast<uint4*>(in_tile + row * 512 + ((2 * cp) ^ ((row & 7) << 4))) = v;
    }
  } else {
    #pragma unroll
    for (int i = 0; i < 4; ++i) {
      int idx = t + i * THREADS;           // 2048 chunks of 4 floats
      int row = idx >> 5;
      int cp  = (idx & 31) * 4;
      float4 v = *reinterpret_cast<const float4*>(x + (row0 + row) * D_ + cp);
      ushort4 o;
      o.x = f2bf(v.x); o.y = f2bf(v.y); o.z = f2bf(v.z); o.w = f2bf(v.w);
      *reinterpret_cast<ushort4*>(in_tile + row * 512 + ((2 * cp) ^ ((row & 7) << 4))) = o;
    }
  }
  __syncthreads();

  // ---- gather + mean into feats 128..255: 32 lanes per row, 4 cols each ----
  {
    const int g  = t & 31;
    const int rb = t >> 5;               // 0..15
    const int c0 = g * 4;
    #pragma unroll
    for (int batch = 0; batch < 4; ++batch) {
      int row = rb + batch * 16;
      const int* ap = adj_lds + row * K_;
      float a0 = 0.f, a1 = 0.f, a2 = 0.f, a3 = 0.f;
      #pragma unroll 8
      for (int k = 0; k < K_; ++k) {
        int a = ap[k];
        if constexpr (USE_BF16) {
          ushort4 v = *reinterpret_cast<const ushort4*>(xh + ((long)bidx * N_ + a) * D_ + c0);
          a0 += bf2f(v.x); a1 += bf2f(v.y); a2 += bf2f(v.z); a3 += bf2f(v.w);
        } else {
          float4 v = *reinterpret_cast<const float4*>(x + ((long)bidx * N_ + a) * D_ + c0);
          a0 += v.x; a1 += v.y; a2 += v.z; a3 += v.w;
        }
      }
      ushort4 m;
      m.x = f2bf(a0 * 0.03125f); m.y = f2bf(a1 * 0.03125f);
      m.z = f2bf(a2 * 0.03125f); m.w = f2bf(a3 * 0.03125f);
      *reinterpret_cast<ushort4*>(in_tile + row * 512 +
                                  ((2 * (D_ + c0)) ^ ((row & 7) << 4))) = m;
    }
  }
  __syncthreads();

  // ---- GEMM: acc[r] (rows r*16..r*16+15) x wave's 16 cols, K=256 ----
  f32x4 acc[4];
  #pragma unroll
  for (int r = 0; r < 4; ++r) acc[r] = (f32x4){0.f, 0.f, 0.f, 0.f};
  #pragma unroll
  for (int ks = 0; ks < 8; ++ks) {
    #pragma unroll
    for (int r = 0; r < 4; ++r) {
      int row = r * 16 + l15;
      int f0  = ks * 32 + kg * 8;
      short8 af = *reinterpret_cast<const short8*>(
          in_tile + row * 512 + ((2 * f0) ^ ((row & 7) << 4)));
      acc[r] = __builtin_amdgcn_mfma_f32_16x16x32_bf16(af, bw[ks], acc[r], 0, 0, 0);
    }
  }

  // ---- epilogue: bias + exact GELU + f32 residual -> y_lds ----
  const float bv = bias[dl];
  #pragma unroll
  for (int r = 0; r < 4; ++r) {
    #pragma unroll
    for (int i = 0; i < 4; ++i) {
      int row = r * 16 + kg * 4 + i;
      float h  = acc[r][i] + bv;
      float ge = 0.5f * h * (1.f + erff(h * 0.70710678118f));
      y_lds[row][dl] = ge + x[(row0 + row) * D_ + dl];
    }
  }
  __syncthreads();

  // ---- LayerNorm per row (8 lanes/row, 16 vals each) + coalesced store ----
  {
    const int row = t >> 3;
    const int l8  = t & 7;
    const float* yr = &y_lds[row][l8 * 16];
    float4 v[4];
    float s = 0.f, sq = 0.f;
    #pragma unroll
    for (int i = 0; i < 4; ++i) {
      v[i] = *reinterpret_cast<const float4*>(yr + i * 4);
      s  += v[i].x + v[i].y + v[i].z + v[i].w;
      sq += v[i].x * v[i].x + v[i].y * v[i].y + v[i].z * v[i].z + v[i].w * v[i].w;
    }
    #pragma unroll
    for (int off = 1; off < 8; off <<= 1) {
      s  += __shfl_xor(s, off, 64);
      sq += __shfl_xor(sq, off, 64);
    }
    const float mu   = s * (1.f / 128.f);
    const float rstd = rsqrtf(sq * (1.f / 128.f) - mu * mu + 1e-5f);
    float* orow = out + (row0 + row) * D_ + l8 * 16;
    #pragma unroll
    for (int i = 0; i < 4; ++i) {
      float4 g  = *reinterpret_cast<const float4*>(gamma + l8 * 16 + i * 4);
      float4 bb = *reinterpret_cast<const float4*>(beta  + l8 * 16 + i * 4);
      float4 o;
      o.x = (v[i].x - mu) * rstd * g.x + bb.x;
      o.y = (v[i].y - mu) * rstd * g.y + bb.y;
      o.z = (v[i].z - mu) * rstd * g.z + bb.z;
      o.w = (v[i].w - mu) * rstd * g.w + bb.w;
      *reinterpret_cast<float4*>(orow + i * 4) = o;
    }
  }
}

extern "C" void kernel_launch(void* const* d_in, const int* in_sizes, int n_in,
                              void* d_out, int out_size, void* d_ws, size_t ws_size,
                              hipStream_t stream) {
  const float* x     = (const float*)d_in[0];
  const int*   adj   = (const int*)d_in[1];
  const float* W     = (const float*)d_in[2];
  const float* bias  = (const float*)d_in[3];
  const float* gamma = (const float*)d_in[4];
  const float* beta  = (const float*)d_in[5];
  float* out = (float*)d_out;

  const size_t xh_bytes = (size_t)B_ * N_ * D_ * 2;
  const int nblocks = (B_ * N_) / BM;   // 512

  if (ws_size >= xh_bytes) {
    unsigned short* xh = (unsigned short*)d_ws;
    const int n4 = B_ * N_ * D_ / 4;    // 1048576
    cvt_kernel<<<dim3(n4 / 256), dim3(256), 0, stream>>>((const float4*)x, (ushort4*)xh, n4);
    fused_kernel<true><<<dim3(nblocks), dim3(THREADS), 0, stream>>>(
        x, adj, W, bias, gamma, beta, xh, out);
  } else {
    fused_kernel<false><<<dim3(nblocks), dim3(THREADS), 0, stream>>>(
        x, adj, W, bias, gamma, beta, nullptr, out);
  }
}

// Round 2
// 116.806 us; speedup vs baseline: 1.0001x; 1.0001x over previous
//
#include <hip/hip_runtime.h>

#define B_ 4
#define N_ 8192
#define D_ 128
#define K_ 32
#define BM 64
#define THREADS 512
#define N4X (B_ * N_ * D_ / 4)   // 1048576 float4 chunks of x
#define NW (2 * D_ * D_)         // 32768 W elements
#define YSTR 132                 // padded y row stride (floats)

typedef short short8 __attribute__((ext_vector_type(8)));
typedef float f32x4 __attribute__((ext_vector_type(4)));

__device__ __forceinline__ unsigned short f2bf(float f) {
  unsigned int u = __float_as_uint(f);
  u += 0x7FFFu + ((u >> 16) & 1u);   // round-to-nearest-even
  return (unsigned short)(u >> 16);
}
__device__ __forceinline__ float bf2f(unsigned short h) {
  return __uint_as_float(((unsigned int)h) << 16);
}

// Converts x -> bf16 (xh) and W -> bf16 transposed (Wt[d][f], f contiguous)
__global__ __launch_bounds__(256) void cvt_kernel(const float4* __restrict__ x,
                                                  ushort4* __restrict__ xh,
                                                  const float* __restrict__ W,
                                                  unsigned short* __restrict__ Wt) {
  int i = blockIdx.x * 256 + threadIdx.x;
  if (i < N4X) {
    float4 v = x[i];
    ushort4 o;
    o.x = f2bf(v.x); o.y = f2bf(v.y); o.z = f2bf(v.z); o.w = f2bf(v.w);
    xh[i] = o;
  } else {
    int e = i - N4X;
    if (e < NW) {
      int f = e >> 7, d = e & 127;
      Wt[d * 256 + f] = f2bf(W[e]);
    }
  }
}

// Fused: gather+mean -> [64x256]x[256x128] bf16 MFMA GEMM -> GELU -> +x -> LayerNorm
template<bool USE_BF16>
__global__ __launch_bounds__(THREADS, 8) void fused_kernel(
    const float* __restrict__ x, const int* __restrict__ adj,
    const float* __restrict__ W, const float* __restrict__ bias,
    const float* __restrict__ gamma, const float* __restrict__ beta,
    const unsigned short* __restrict__ xh, const unsigned short* __restrict__ Wt,
    float* __restrict__ out) {

  // Phase A: in_tile [64 rows][512B bf16, XOR-swizzled byte^=(row&7)<<4] + adj (8KB)
  // Phase B: y [64][YSTR] f32 (aliases in_tile+adj head)
  __shared__ __align__(16) unsigned char smem[40960];
  unsigned char* in_tile = smem;
  int* adj_lds = (int*)(smem + 32768);
  float* y = (float*)smem;

  const int t    = threadIdx.x;
  const int wave = t >> 6;
  const int lane = t & 63;
  const int l15  = lane & 15;
  const int kg   = lane >> 4;          // k-group 0..3

  // XCD swizzle: 512 blocks round-robin 8 XCDs -> give each XCD 64 contiguous
  // tiles (one half-batch; 2MB bf16 x fits its 4MB L2)
  const int  vid  = (blockIdx.x & 7) * 64 + (blockIdx.x >> 3);
  const int  bidx = vid >> 7;          // batch
  const int  n0   = (vid & 127) * BM;
  const long row0 = (long)bidx * N_ + n0;

  // ---- stage adj tile (coalesced) ----
  #pragma unroll
  for (int i = 0; i < (BM * K_) / THREADS; ++i)
    adj_lds[t + i * THREADS] = adj[row0 * K_ + t + i * THREADS];

  // ---- stage x rows into feats 0..127 (bf16, swizzled) ----
  if constexpr (USE_BF16) {
    #pragma unroll
    for (int i = 0; i < 2; ++i) {
      int idx = t + i * THREADS;           // 1024 chunks of 8 bf16
      int row = idx >> 4;
      int cp  = (idx & 15) * 8;
      uint4 v = *reinterpret_cast<const uint4*>(xh + (row0 + row) * D_ + cp);
      *reinterpret_cast<uint4*>(in_tile + row * 512 + ((2 * cp) ^ ((row & 7) << 4))) = v;
    }
  } else {
    #pragma unroll
    for (int i = 0; i < 4; ++i) {
      int idx = t + i * THREADS;           // 2048 chunks of 4 floats
      int row = idx >> 5;
      int cp  = (idx & 31) * 4;
      float4 v = *reinterpret_cast<const float4*>(x + (row0 + row) * D_ + cp);
      ushort4 o;
      o.x = f2bf(v.x); o.y = f2bf(v.y); o.z = f2bf(v.z); o.w = f2bf(v.w);
      *reinterpret_cast<ushort4*>(in_tile + row * 512 + ((2 * cp) ^ ((row & 7) << 4))) = o;
    }
  }
  __syncthreads();

  // ---- gather + mean into feats 128..255 ----
  if constexpr (USE_BF16) {
    // 16 lanes per row, 8 bf16 (16B) per lane
    const int g16 = t & 15;
    const int rb  = t >> 4;              // 0..31
    const int c0  = g16 * 8;
    #pragma unroll
    for (int half = 0; half < 2; ++half) {
      int row = rb + half * 32;
      const int* ap = adj_lds + row * K_;
      float a[8] = {0.f, 0.f, 0.f, 0.f, 0.f, 0.f, 0.f, 0.f};
      #pragma unroll 8
      for (int k = 0; k < K_; ++k) {
        uint4 v = *reinterpret_cast<const uint4*>(
            xh + ((long)bidx * N_ + ap[k]) * D_ + c0);
        const unsigned short* pv = (const unsigned short*)&v;
        #pragma unroll
        for (int j = 0; j < 8; ++j) a[j] += bf2f(pv[j]);
      }
      unsigned short m[8];
      #pragma unroll
      for (int j = 0; j < 8; ++j) m[j] = f2bf(a[j] * 0.03125f);
      *reinterpret_cast<uint4*>(in_tile + row * 512 +
                                ((256 + 2 * c0) ^ ((row & 7) << 4))) =
          *reinterpret_cast<uint4*>(m);
    }
  } else {
    const int g  = t & 31;
    const int rb = t >> 5;               // 0..15
    const int c0 = g * 4;
    #pragma unroll
    for (int batch = 0; batch < 4; ++batch) {
      int row = rb + batch * 16;
      const int* ap = adj_lds + row * K_;
      float a0 = 0.f, a1 = 0.f, a2 = 0.f, a3 = 0.f;
      #pragma unroll 8
      for (int k = 0; k < K_; ++k) {
        float4 v = *reinterpret_cast<const float4*>(
            x + ((long)bidx * N_ + ap[k]) * D_ + c0);
        a0 += v.x; a1 += v.y; a2 += v.z; a3 += v.w;
      }
      ushort4 m;
      m.x = f2bf(a0 * 0.03125f); m.y = f2bf(a1 * 0.03125f);
      m.z = f2bf(a2 * 0.03125f); m.w = f2bf(a3 * 0.03125f);
      *reinterpret_cast<ushort4*>(in_tile + row * 512 +
                                  ((2 * (D_ + c0)) ^ ((row & 7) << 4))) = m;
    }
  }
  __syncthreads();

  // ---- GEMM: acc[r] (rows r*16..r*16+15) x wave's 16 cols, K=256 ----
  const int dl = (wave << 4) + l15;
  f32x4 acc[4];
  #pragma unroll
  for (int r = 0; r < 4; ++r) acc[r] = (f32x4){0.f, 0.f, 0.f, 0.f};
  #pragma unroll
  for (int ks = 0; ks < 8; ++ks) {
    short8 bwk;
    if constexpr (USE_BF16) {
      bwk = *reinterpret_cast<const short8*>(Wt + dl * 256 + ks * 32 + kg * 8);
    } else {
      #pragma unroll
      for (int j = 0; j < 8; ++j)
        bwk[j] = (short)f2bf(W[(ks * 32 + kg * 8 + j) * D_ + dl]);
    }
    #pragma unroll
    for (int r = 0; r < 4; ++r) {
      int row = r * 16 + l15;
      short8 af = *reinterpret_cast<const short8*>(
          in_tile + row * 512 + ((2 * (ks * 32 + kg * 8)) ^ ((row & 7) << 4)));
      acc[r] = __builtin_amdgcn_mfma_f32_16x16x32_bf16(af, bwk, acc[r], 0, 0, 0);
    }
  }
  __syncthreads();   // all in_tile reads done before y aliases it

  // ---- epilogue: bias + exact GELU + f32 residual -> y ----
  const float bv = bias[dl];
  #pragma unroll
  for (int r = 0; r < 4; ++r) {
    #pragma unroll
    for (int i = 0; i < 4; ++i) {
      int row = r * 16 + kg * 4 + i;
      float h  = acc[r][i] + bv;
      float ge = 0.5f * h * (1.f + erff(h * 0.70710678118f));
      y[row * YSTR + dl] = ge + x[(row0 + row) * D_ + dl];
    }
  }
  __syncthreads();

  // ---- LayerNorm per row (8 lanes/row, 16 vals each) + coalesced store ----
  {
    const int row = t >> 3;
    const int l8  = t & 7;
    const float* yr = y + row * YSTR + l8 * 16;
    float4 v[4];
    float s = 0.f, sq = 0.f;
    #pragma unroll
    for (int i = 0; i < 4; ++i) {
      v[i] = *reinterpret_cast<const float4*>(yr + i * 4);
      s  += v[i].x + v[i].y + v[i].z + v[i].w;
      sq += v[i].x * v[i].x + v[i].y * v[i].y + v[i].z * v[i].z + v[i].w * v[i].w;
    }
    #pragma unroll
    for (int off = 1; off < 8; off <<= 1) {
      s  += __shfl_xor(s, off, 64);
      sq += __shfl_xor(sq, off, 64);
    }
    const float mu   = s * (1.f / 128.f);
    const float rstd = rsqrtf(sq * (1.f / 128.f) - mu * mu + 1e-5f);
    float* orow = out + (row0 + row) * D_ + l8 * 16;
    #pragma unroll
    for (int i = 0; i < 4; ++i) {
      float4 g  = *reinterpret_cast<const float4*>(gamma + l8 * 16 + i * 4);
      float4 bb = *reinterpret_cast<const float4*>(beta  + l8 * 16 + i * 4);
      float4 o;
      o.x = (v[i].x - mu) * rstd * g.x + bb.x;
      o.y = (v[i].y - mu) * rstd * g.y + bb.y;
      o.z = (v[i].z - mu) * rstd * g.z + bb.z;
      o.w = (v[i].w - mu) * rstd * g.w + bb.w;
      *reinterpret_cast<float4*>(orow + i * 4) = o;
    }
  }
}

extern "C" void kernel_launch(void* const* d_in, const int* in_sizes, int n_in,
                              void* d_out, int out_size, void* d_ws, size_t ws_size,
                              hipStream_t stream) {
  const float* x     = (const float*)d_in[0];
  const int*   adj   = (const int*)d_in[1];
  const float* W     = (const float*)d_in[2];
  const float* bias  = (const float*)d_in[3];
  const float* gamma = (const float*)d_in[4];
  const float* beta  = (const float*)d_in[5];
  float* out = (float*)d_out;

  const size_t xh_bytes = (size_t)B_ * N_ * D_ * 2;      // 8 MB
  const size_t wt_bytes = (size_t)NW * 2;                // 64 KB
  const int nblocks = (B_ * N_) / BM;                    // 512

  if (ws_size >= xh_bytes + wt_bytes) {
    unsigned short* xh = (unsigned short*)d_ws;
    unsigned short* Wt = (unsigned short*)((char*)d_ws + xh_bytes);
    const int ncvt = (N4X + NW + 255) / 256;             // 4224
    cvt_kernel<<<dim3(ncvt), dim3(256), 0, stream>>>((const float4*)x, (ushort4*)xh, W, Wt);
    fused_kernel<true><<<dim3(nblocks), dim3(THREADS), 0, stream>>>(
        x, adj, W, bias, gamma, beta, xh, Wt, out);
  } else {
    fused_kernel<false><<<dim3(nblocks), dim3(THREADS), 0, stream>>>(
        x, adj, W, bias, gamma, beta, nullptr, nullptr, out);
  }
}

// Round 7
// 110.271 us; speedup vs baseline: 1.0594x; 1.0593x over previous
//
#include <hip/hip_runtime.h>

#define B_ 4
#define N_ 8192
#define D_ 128
#define K_ 32

typedef short short8 __attribute__((ext_vector_type(8)));
typedef float f32x4 __attribute__((ext_vector_type(4)));

__device__ __forceinline__ unsigned short f2bf(float f) {
  unsigned int u = __float_as_uint(f);
  u += 0x7FFFu + ((u >> 16) & 1u);   // round-to-nearest-even
  return (unsigned short)(u >> 16);
}
__device__ __forceinline__ float bf2f(unsigned short h) {
  return __uint_as_float(((unsigned int)h) << 16);
}

// ---------------- K1: P = X * W  (U = X*W1 -> f32, V = X*W2 -> bf16) --------
// 1024 blocks x 512 thr; each block: 32 rows x 256 out-cols, K=128.
// Waves 0-3 compute U cols, waves 4-7 compute V cols (32 cols each).
__global__ __launch_bounds__(512) void gemm_kernel(
    const float* __restrict__ x, const float* __restrict__ W,
    float* __restrict__ p1, unsigned short* __restrict__ p2h) {
  __shared__ __align__(16) unsigned char in_tile[32 * 256];  // bf16, swizzled

  const int t = threadIdx.x, wave = t >> 6, lane = t & 63;
  const int l15 = lane & 15, kg = lane >> 4;
  const long row0 = (long)blockIdx.x * 32;

  // stage 32x128 f32 -> bf16 LDS (byte ^= (row&7)<<4)
  #pragma unroll
  for (int i = 0; i < 2; ++i) {
    int idx = t + i * 512;
    int row = idx >> 5, cs = idx & 31;
    float4 v = *reinterpret_cast<const float4*>(x + (row0 + row) * D_ + cs * 4);
    ushort4 o;
    o.x = f2bf(v.x); o.y = f2bf(v.y); o.z = f2bf(v.z); o.w = f2bf(v.w);
    *reinterpret_cast<ushort4*>(
        in_tile + ((row * 256 + cs * 8) ^ ((row & 7) << 4))) = o;
  }

  // B fragments from W (f32 -> bf16), 2 n-tiles x 4 k-steps
  const int halfw = wave & 3, is_v = wave >> 2;
  const float* Wb = W + (is_v ? D_ * D_ : 0);
  short8 bw[2][4];
  #pragma unroll
  for (int tt = 0; tt < 2; ++tt)
    #pragma unroll
    for (int ks = 0; ks < 4; ++ks)
      #pragma unroll
      for (int j = 0; j < 8; ++j)
        bw[tt][ks][j] = (short)f2bf(
            Wb[(ks * 32 + kg * 8 + j) * D_ + halfw * 32 + tt * 16 + l15]);
  __syncthreads();

  f32x4 acc[2][2];
  #pragma unroll
  for (int r = 0; r < 2; ++r)
    #pragma unroll
    for (int tt = 0; tt < 2; ++tt)
      acc[r][tt] = (f32x4){0.f, 0.f, 0.f, 0.f};

  #pragma unroll
  for (int ks = 0; ks < 4; ++ks) {
    #pragma unroll
    for (int r = 0; r < 2; ++r) {
      int row = r * 16 + l15;
      short8 af = *reinterpret_cast<const short8*>(
          in_tile + ((row * 256 + ks * 64 + kg * 16) ^ ((row & 7) << 4)));
      acc[r][0] = __builtin_amdgcn_mfma_f32_16x16x32_bf16(af, bw[0][ks], acc[r][0], 0, 0, 0);
      acc[r][1] = __builtin_amdgcn_mfma_f32_16x16x32_bf16(af, bw[1][ks], acc[r][1], 0, 0, 0);
    }
  }

  #pragma unroll
  for (int r = 0; r < 2; ++r)
    #pragma unroll
    for (int tt = 0; tt < 2; ++tt)
      #pragma unroll
      for (int i = 0; i < 4; ++i) {
        int row = r * 16 + kg * 4 + i;
        int col = halfw * 32 + tt * 16 + l15;
        float val = acc[r][tt][i];
        if (!is_v) p1[(row0 + row) * D_ + col] = val;
        else       p2h[(row0 + row) * D_ + col] = f2bf(val);
      }
}

// ---------------- K2: out[n] = LN(gelu(U[n] + mean_k V[adj[n,k]] + b) + x[n])
// 2048 blocks x 256 thr (4 waves). One node per wave iteration, 4 nodes/wave.
// Lane owns 2 feature columns (dword of V per gather load).
__global__ __launch_bounds__(256) void gather_kernel(
    const int* __restrict__ adj, const float* __restrict__ p1,
    const unsigned short* __restrict__ p2h, const float* __restrict__ x,
    const float* __restrict__ bias, const float* __restrict__ gamma,
    const float* __restrict__ beta, float* __restrict__ out) {
  const int t = threadIdx.x;
  const int wave = t >> 6, lane = t & 63;
  // XCD swizzle (2048 = 8*256): XCD g gets contiguous node range (half a batch)
  const int vblk = ((blockIdx.x & 7) << 8) + (blockIdx.x >> 3);
  const int node_base = vblk * 16 + wave * 4;
  const int b = node_base >> 13;
  const unsigned int* vb =
      (const unsigned int*)p2h + (size_t)b * (N_ * (D_ / 2));  // dword units
  const int c0 = lane * 2;
  const float2 bi = *reinterpret_cast<const float2*>(bias + c0);
  const float2 ga = *reinterpret_cast<const float2*>(gamma + c0);
  const float2 be = *reinterpret_cast<const float2*>(beta + c0);
  // force scalar (s_load) path for adj
  const int nbu = __builtin_amdgcn_readfirstlane(node_base);

  #pragma unroll
  for (int j = 0; j < 4; ++j) {
    const int gn = nbu + j;
    const int* ap = adj + (size_t)gn * K_;   // uniform -> s_load_dwordx8
    float a0 = 0.f, a1 = 0.f;
    #pragma unroll
    for (int k = 0; k < K_; ++k) {
      unsigned int v = vb[(size_t)ap[k] * (D_ / 2) + lane];
      a0 += __uint_as_float(v << 16);
      a1 += __uint_as_float(v & 0xFFFF0000u);
    }
    const float2 u  = *reinterpret_cast<const float2*>(p1 + (size_t)gn * D_ + c0);
    const float2 xv = *reinterpret_cast<const float2*>(x  + (size_t)gn * D_ + c0);
    float h0 = u.x + a0 * 0.03125f + bi.x;
    float h1 = u.y + a1 * 0.03125f + bi.y;
    h0 = 0.5f * h0 * (1.f + erff(h0 * 0.70710678118f));
    h1 = 0.5f * h1 * (1.f + erff(h1 * 0.70710678118f));
    const float y0 = h0 + xv.x, y1 = h1 + xv.y;
    float s = y0 + y1, sq = y0 * y0 + y1 * y1;
    #pragma unroll
    for (int off = 1; off < 64; off <<= 1) {
      s  += __shfl_xor(s, off, 64);
      sq += __shfl_xor(sq, off, 64);
    }
    const float mu   = s * (1.f / 128.f);
    const float rstd = rsqrtf(sq * (1.f / 128.f) - mu * mu + 1e-5f);
    float2 o;
    o.x = (y0 - mu) * rstd * ga.x + be.x;
    o.y = (y1 - mu) * rstd * ga.y + be.y;
    *reinterpret_cast<float2*>(out + (size_t)gn * D_ + c0) = o;
  }
}

// ---------------- fallback (no workspace): monolithic f32 path --------------
__global__ __launch_bounds__(512) void fused_f32_kernel(
    const float* __restrict__ x, const int* __restrict__ adj,
    const float* __restrict__ W, const float* __restrict__ bias,
    const float* __restrict__ gamma, const float* __restrict__ beta,
    float* __restrict__ out) {
  __shared__ __align__(16) unsigned char smem[40960];
  unsigned char* in_tile = smem;
  int* adj_lds = (int*)(smem + 32768);
  float* y = (float*)smem;
  const int t = threadIdx.x, wave = t >> 6, lane = t & 63;
  const int l15 = lane & 15, kg = lane >> 4;
  const int vid = (blockIdx.x & 7) * 64 + (blockIdx.x >> 3);
  const int bidx = vid >> 7;
  const long row0 = (long)bidx * N_ + (vid & 127) * 64;
  #pragma unroll
  for (int i = 0; i < 4; ++i)
    adj_lds[t + i * 512] = adj[row0 * K_ + t + i * 512];
  #pragma unroll
  for (int i = 0; i < 4; ++i) {
    int idx = t + i * 512;
    int row = idx >> 5, cp = (idx & 31) * 4;
    float4 v = *reinterpret_cast<const float4*>(x + (row0 + row) * D_ + cp);
    ushort4 o;
    o.x = f2bf(v.x); o.y = f2bf(v.y); o.z = f2bf(v.z); o.w = f2bf(v.w);
    *reinterpret_cast<ushort4*>(in_tile + row * 512 + ((2 * cp) ^ ((row & 7) << 4))) = o;
  }
  __syncthreads();
  {
    const int g = t & 31, rb = t >> 5, c0 = g * 4;
    #pragma unroll
    for (int batch = 0; batch < 4; ++batch) {
      int row = rb + batch * 16;
      const int* ap = adj_lds + row * K_;
      float a0 = 0, a1 = 0, a2 = 0, a3 = 0;
      for (int k = 0; k < K_; ++k) {
        float4 v = *reinterpret_cast<const float4*>(x + ((long)bidx * N_ + ap[k]) * D_ + c0);
        a0 += v.x; a1 += v.y; a2 += v.z; a3 += v.w;
      }
      ushort4 m;
      m.x = f2bf(a0 * 0.03125f); m.y = f2bf(a1 * 0.03125f);
      m.z = f2bf(a2 * 0.03125f); m.w = f2bf(a3 * 0.03125f);
      *reinterpret_cast<ushort4*>(in_tile + row * 512 +
                                  ((2 * (D_ + c0)) ^ ((row & 7) << 4))) = m;
    }
  }
  __syncthreads();
  const int dl = (wave << 4) + l15;
  f32x4 acc[4];
  #pragma unroll
  for (int r = 0; r < 4; ++r) acc[r] = (f32x4){0.f, 0.f, 0.f, 0.f};
  #pragma unroll
  for (int ks = 0; ks < 8; ++ks) {
    short8 bwk;
    #pragma unroll
    for (int j = 0; j < 8; ++j)
      bwk[j] = (short)f2bf(W[(ks * 32 + kg * 8 + j) * D_ + dl]);
    #pragma unroll
    for (int r = 0; r < 4; ++r) {
      int row = r * 16 + l15;
      short8 af = *reinterpret_cast<const short8*>(
          in_tile + row * 512 + ((2 * (ks * 32 + kg * 8)) ^ ((row & 7) << 4)));
      acc[r] = __builtin_amdgcn_mfma_f32_16x16x32_bf16(af, bwk, acc[r], 0, 0, 0);
    }
  }
  __syncthreads();
  const float bv = bias[dl];
  #pragma unroll
  for (int r = 0; r < 4; ++r)
    #pragma unroll
    for (int i = 0; i < 4; ++i) {
      int row = r * 16 + kg * 4 + i;
      float h = acc[r][i] + bv;
      float ge = 0.5f * h * (1.f + erff(h * 0.70710678118f));
      y[row * 132 + dl] = ge + x[(row0 + row) * D_ + dl];
    }
  __syncthreads();
  {
    const int row = t >> 3, l8 = t & 7;
    const float* yr = y + row * 132 + l8 * 16;
    float4 v[4];
    float s = 0.f, sq = 0.f;
    #pragma unroll
    for (int i = 0; i < 4; ++i) {
      v[i] = *reinterpret_cast<const float4*>(yr + i * 4);
      s += v[i].x + v[i].y + v[i].z + v[i].w;
      sq += v[i].x * v[i].x + v[i].y * v[i].y + v[i].z * v[i].z + v[i].w * v[i].w;
    }
    #pragma unroll
    for (int off = 1; off < 8; off <<= 1) {
      s += __shfl_xor(s, off, 64);
      sq += __shfl_xor(sq, off, 64);
    }
    const float mu = s * (1.f / 128.f);
    const float rstd = rsqrtf(sq * (1.f / 128.f) - mu * mu + 1e-5f);
    float* orow = out + (row0 + row) * D_ + l8 * 16;
    #pragma unroll
    for (int i = 0; i < 4; ++i) {
      float4 g = *reinterpret_cast<const float4*>(gamma + l8 * 16 + i * 4);
      float4 bb = *reinterpret_cast<const float4*>(beta + l8 * 16 + i * 4);
      float4 o;
      o.x = (v[i].x - mu) * rstd * g.x + bb.x;
      o.y = (v[i].y - mu) * rstd * g.y + bb.y;
      o.z = (v[i].z - mu) * rstd * g.z + bb.z;
      o.w = (v[i].w - mu) * rstd * g.w + bb.w;
      *reinterpret_cast<float4*>(orow + i * 4) = o;
    }
  }
}

extern "C" void kernel_launch(void* const* d_in, const int* in_sizes, int n_in,
                              void* d_out, int out_size, void* d_ws, size_t ws_size,
                              hipStream_t stream) {
  const float* x     = (const float*)d_in[0];
  const int*   adj   = (const int*)d_in[1];
  const float* W     = (const float*)d_in[2];
  const float* bias  = (const float*)d_in[3];
  const float* gamma = (const float*)d_in[4];
  const float* beta  = (const float*)d_in[5];
  float* out = (float*)d_out;

  const size_t p1_bytes = (size_t)B_ * N_ * D_ * 4;   // 16 MB f32 U
  const size_t p2_bytes = (size_t)B_ * N_ * D_ * 2;   // 8 MB bf16 V

  if (ws_size >= p1_bytes + p2_bytes) {
    float* p1 = (float*)d_ws;
    unsigned short* p2h = (unsigned short*)((char*)d_ws + p1_bytes);
    gemm_kernel<<<dim3((B_ * N_) / 32), dim3(512), 0, stream>>>(x, W, p1, p2h);
    gather_kernel<<<dim3(2048), dim3(256), 0, stream>>>(
        adj, p1, p2h, x, bias, gamma, beta, out);
  } else {
    fused_f32_kernel<<<dim3((B_ * N_) / 64), dim3(512), 0, stream>>>(
        x, adj, W, bias, gamma, beta, out);
  }
}

// Round 11
// 108.385 us; speedup vs baseline: 1.0779x; 1.0174x over previous
//
#include <hip/hip_runtime.h>

#define B_ 4
#define N_ 8192
#define D_ 128
#define K_ 32

typedef short short8 __attribute__((ext_vector_type(8)));
typedef float f32x4 __attribute__((ext_vector_type(4)));

__device__ __forceinline__ unsigned short f2bf(float f) {
  unsigned int u = __float_as_uint(f);
  u += 0x7FFFu + ((u >> 16) & 1u);   // round-to-nearest-even
  return (unsigned short)(u >> 16);
}
__device__ __forceinline__ float bf2f(unsigned short h) {
  return __uint_as_float(((unsigned int)h) << 16);
}

// ---------- K0: Wt[col256][floc128] bf16, col256 = is_v*128 + d ------------
// Wt[(is_v*128 + d)*128 + floc] = W[(is_v*128 + floc)*128 + d]
__global__ __launch_bounds__(256) void cvt_w_kernel(const float* __restrict__ W,
                                                    unsigned short* __restrict__ Wt) {
  int e = blockIdx.x * 256 + threadIdx.x;      // 32768 elements, coalesced read
  int d = e & 127, fglob = e >> 7;
  int is_v = fglob >> 7, floc = fglob & 127;
  Wt[(is_v * 128 + d) * 128 + floc] = f2bf(W[e]);
}

// ---------- K1: P[row][256] bf16 = [X*W1 | X*W2]  (M=64/block, 512 blocks) --
// 8 waves: wave w -> is_v = w>>2 (U/V half), halfw = w&3 -> 32 cols.
// acc[4 rowtiles][2 coltiles]; K=128 in 4 MFMA k-steps.
__global__ __launch_bounds__(512) void gemm_kernel(
    const float* __restrict__ x, const unsigned short* __restrict__ Wt,
    unsigned short* __restrict__ P) {
  __shared__ __align__(16) unsigned char in_tile[64 * 256];  // bf16, swizzled

  const int t = threadIdx.x, wave = t >> 6, lane = t & 63;
  const int l15 = lane & 15, kg = lane >> 4;
  const long row0 = (long)blockIdx.x * 64;

  // stage 64x128 f32 -> bf16 LDS (byte ^= (row&7)<<4)
  #pragma unroll
  for (int i = 0; i < 4; ++i) {
    int idx = t + i * 512;                     // 2048 float4 chunks
    int row = idx >> 5, cs = idx & 31;
    float4 v = *reinterpret_cast<const float4*>(x + (row0 + row) * D_ + cs * 4);
    ushort4 o;
    o.x = f2bf(v.x); o.y = f2bf(v.y); o.z = f2bf(v.z); o.w = f2bf(v.w);
    *reinterpret_cast<ushort4*>(
        in_tile + ((row * 256 + cs * 8) ^ ((row & 7) << 4))) = o;
  }

  // B fragments from Wt: 2 coltiles x 4 k-steps, each one 16B load
  const int halfw = wave & 3, is_v = wave >> 2;
  short8 bw[2][4];
  #pragma unroll
  for (int tt = 0; tt < 2; ++tt) {
    const int col = is_v * 128 + halfw * 32 + tt * 16 + l15;
    #pragma unroll
    for (int ks = 0; ks < 4; ++ks)
      bw[tt][ks] = *reinterpret_cast<const short8*>(
          Wt + col * 128 + ks * 32 + kg * 8);
  }
  __syncthreads();

  f32x4 acc[4][2];
  #pragma unroll
  for (int r = 0; r < 4; ++r)
    #pragma unroll
    for (int tt = 0; tt < 2; ++tt)
      acc[r][tt] = (f32x4){0.f, 0.f, 0.f, 0.f};

  #pragma unroll
  for (int ks = 0; ks < 4; ++ks) {
    #pragma unroll
    for (int r = 0; r < 4; ++r) {
      int row = r * 16 + l15;
      short8 af = *reinterpret_cast<const short8*>(
          in_tile + ((row * 256 + ks * 64 + kg * 16) ^ ((row & 7) << 4)));
      acc[r][0] = __builtin_amdgcn_mfma_f32_16x16x32_bf16(af, bw[0][ks], acc[r][0], 0, 0, 0);
      acc[r][1] = __builtin_amdgcn_mfma_f32_16x16x32_bf16(af, bw[1][ks], acc[r][1], 0, 0, 0);
    }
  }

  #pragma unroll
  for (int r = 0; r < 4; ++r)
    #pragma unroll
    for (int tt = 0; tt < 2; ++tt) {
      const int col = is_v * 128 + halfw * 32 + tt * 16 + l15;
      #pragma unroll
      for (int i = 0; i < 4; ++i) {
        int row = r * 16 + kg * 4 + i;
        P[(row0 + row) * 256 + col] = f2bf(acc[r][tt][i]);
      }
    }
}

// ---------- K2: out[n] = LN(gelu(U[n] + mean_k V[adj[n,k]] + b) + x[n]) -----
// 2048 blocks x 256 thr; 4 nodes/wave; lane owns 2 feature cols (1 dword/row).
__global__ __launch_bounds__(256) void gather_kernel(
    const int* __restrict__ adj, const unsigned short* __restrict__ P,
    const float* __restrict__ x, const float* __restrict__ bias,
    const float* __restrict__ gamma, const float* __restrict__ beta,
    float* __restrict__ out) {
  const int t = threadIdx.x;
  const int wave = t >> 6, lane = t & 63;
  // XCD swizzle (2048 = 8*256): each XCD gets a contiguous half-batch
  const int vblk = ((blockIdx.x & 7) << 8) + (blockIdx.x >> 3);
  const int node_base = vblk * 16 + wave * 4;
  const int b = node_base >> 13;
  const unsigned int* pd = (const unsigned int*)P;     // row stride 128 dwords
  const unsigned int* vbase = pd + ((size_t)b << 13) * 128 + 64 + lane;
  const int c0 = lane * 2;
  const float2 bi = *reinterpret_cast<const float2*>(bias + c0);
  const float2 ga = *reinterpret_cast<const float2*>(gamma + c0);
  const float2 be = *reinterpret_cast<const float2*>(beta + c0);
  const int nbu = __builtin_amdgcn_readfirstlane(node_base);  // scalar path

  #pragma unroll
  for (int j = 0; j < 4; ++j) {
    const int gn = nbu + j;
    const int* ap = adj + (size_t)gn * K_;   // uniform -> s_load chains
    float a0 = 0.f, a1 = 0.f;
    #pragma unroll
    for (int k = 0; k < K_; ++k) {
      unsigned int v = vbase[(size_t)ap[k] * 128];
      a0 += __uint_as_float(v << 16);
      a1 += __uint_as_float(v & 0xFFFF0000u);
    }
    const unsigned int ud = pd[(size_t)gn * 128 + lane];
    const float2 xv = *reinterpret_cast<const float2*>(x + (size_t)gn * D_ + c0);
    float h0 = __uint_as_float(ud << 16)        + a0 * 0.03125f + bi.x;
    float h1 = __uint_as_float(ud & 0xFFFF0000u) + a1 * 0.03125f + bi.y;
    h0 = 0.5f * h0 * (1.f + erff(h0 * 0.70710678118f));
    h1 = 0.5f * h1 * (1.f + erff(h1 * 0.70710678118f));
    const float y0 = h0 + xv.x, y1 = h1 + xv.y;
    float s = y0 + y1, sq = y0 * y0 + y1 * y1;
    #pragma unroll
    for (int off = 1; off < 64; off <<= 1) {
      s  += __shfl_xor(s, off, 64);
      sq += __shfl_xor(sq, off, 64);
    }
    const float mu   = s * (1.f / 128.f);
    const float rstd = rsqrtf(sq * (1.f / 128.f) - mu * mu + 1e-5f);
    float2 o;
    o.x = (y0 - mu) * rstd * ga.x + be.x;
    o.y = (y1 - mu) * rstd * ga.y + be.y;
    *reinterpret_cast<float2*>(out + (size_t)gn * D_ + c0) = o;
  }
}

// ---------------- fallback (no workspace): monolithic f32 path --------------
__global__ __launch_bounds__(512) void fused_f32_kernel(
    const float* __restrict__ x, const int* __restrict__ adj,
    const float* __restrict__ W, const float* __restrict__ bias,
    const float* __restrict__ gamma, const float* __restrict__ beta,
    float* __restrict__ out) {
  __shared__ __align__(16) unsigned char smem[40960];
  unsigned char* in_tile = smem;
  int* adj_lds = (int*)(smem + 32768);
  float* y = (float*)smem;
  const int t = threadIdx.x, wave = t >> 6, lane = t & 63;
  const int l15 = lane & 15, kg = lane >> 4;
  const int vid = (blockIdx.x & 7) * 64 + (blockIdx.x >> 3);
  const int bidx = vid >> 7;
  const long row0 = (long)bidx * N_ + (vid & 127) * 64;
  #pragma unroll
  for (int i = 0; i < 4; ++i)
    adj_lds[t + i * 512] = adj[row0 * K_ + t + i * 512];
  #pragma unroll
  for (int i = 0; i < 4; ++i) {
    int idx = t + i * 512;
    int row = idx >> 5, cp = (idx & 31) * 4;
    float4 v = *reinterpret_cast<const float4*>(x + (row0 + row) * D_ + cp);
    ushort4 o;
    o.x = f2bf(v.x); o.y = f2bf(v.y); o.z = f2bf(v.z); o.w = f2bf(v.w);
    *reinterpret_cast<ushort4*>(in_tile + row * 512 + ((2 * cp) ^ ((row & 7) << 4))) = o;
  }
  __syncthreads();
  {
    const int g = t & 31, rb = t >> 5, c0 = g * 4;
    #pragma unroll
    for (int batch = 0; batch < 4; ++batch) {
      int row = rb + batch * 16;
      const int* ap = adj_lds + row * K_;
      float a0 = 0, a1 = 0, a2 = 0, a3 = 0;
      for (int k = 0; k < K_; ++k) {
        float4 v = *reinterpret_cast<const float4*>(x + ((long)bidx * N_ + ap[k]) * D_ + c0);
        a0 += v.x; a1 += v.y; a2 += v.z; a3 += v.w;
      }
      ushort4 m;
      m.x = f2bf(a0 * 0.03125f); m.y = f2bf(a1 * 0.03125f);
      m.z = f2bf(a2 * 0.03125f); m.w = f2bf(a3 * 0.03125f);
      *reinterpret_cast<ushort4*>(in_tile + row * 512 +
                                  ((2 * (D_ + c0)) ^ ((row & 7) << 4))) = m;
    }
  }
  __syncthreads();
  const int dl = (wave << 4) + l15;
  f32x4 acc[4];
  #pragma unroll
  for (int r = 0; r < 4; ++r) acc[r] = (f32x4){0.f, 0.f, 0.f, 0.f};
  #pragma unroll
  for (int ks = 0; ks < 8; ++ks) {
    short8 bwk;
    #pragma unroll
    for (int j = 0; j < 8; ++j)
      bwk[j] = (short)f2bf(W[(ks * 32 + kg * 8 + j) * D_ + dl]);
    #pragma unroll
    for (int r = 0; r < 4; ++r) {
      int row = r * 16 + l15;
      short8 af = *reinterpret_cast<const short8*>(
          in_tile + row * 512 + ((2 * (ks * 32 + kg * 8)) ^ ((row & 7) << 4)));
      acc[r] = __builtin_amdgcn_mfma_f32_16x16x32_bf16(af, bwk, acc[r], 0, 0, 0);
    }
  }
  __syncthreads();
  const float bv = bias[dl];
  #pragma unroll
  for (int r = 0; r < 4; ++r)
    #pragma unroll
    for (int i = 0; i < 4; ++i) {
      int row = r * 16 + kg * 4 + i;
      float h = acc[r][i] + bv;
      float ge = 0.5f * h * (1.f + erff(h * 0.70710678118f));
      y[row * 132 + dl] = ge + x[(row0 + row) * D_ + dl];
    }
  __syncthreads();
  {
    const int row = t >> 3, l8 = t & 7;
    const float* yr = y + row * 132 + l8 * 16;
    float4 v[4];
    float s = 0.f, sq = 0.f;
    #pragma unroll
    for (int i = 0; i < 4; ++i) {
      v[i] = *reinterpret_cast<const float4*>(yr + i * 4);
      s += v[i].x + v[i].y + v[i].z + v[i].w;
      sq += v[i].x * v[i].x + v[i].y * v[i].y + v[i].z * v[i].z + v[i].w * v[i].w;
    }
    #pragma unroll
    for (int off = 1; off < 8; off <<= 1) {
      s += __shfl_xor(s, off, 64);
      sq += __shfl_xor(sq, off, 64);
    }
    const float mu = s * (1.f / 128.f);
    const float rstd = rsqrtf(sq * (1.f / 128.f) - mu * mu + 1e-5f);
    float* orow = out + (row0 + row) * D_ + l8 * 16;
    #pragma unroll
    for (int i = 0; i < 4; ++i) {
      float4 g = *reinterpret_cast<const float4*>(gamma + l8 * 16 + i * 4);
      float4 bb = *reinterpret_cast<const float4*>(beta + l8 * 16 + i * 4);
      float4 o;
      o.x = (v[i].x - mu) * rstd * g.x + bb.x;
      o.y = (v[i].y - mu) * rstd * g.y + bb.y;
      o.z = (v[i].z - mu) * rstd * g.z + bb.z;
      o.w = (v[i].w - mu) * rstd * g.w + bb.w;
      *reinterpret_cast<float4*>(orow + i * 4) = o;
    }
  }
}

extern "C" void kernel_launch(void* const* d_in, const int* in_sizes, int n_in,
                              void* d_out, int out_size, void* d_ws, size_t ws_size,
                              hipStream_t stream) {
  const float* x     = (const float*)d_in[0];
  const int*   adj   = (const int*)d_in[1];
  const float* W     = (const float*)d_in[2];
  const float* bias  = (const float*)d_in[3];
  const float* gamma = (const float*)d_in[4];
  const float* beta  = (const float*)d_in[5];
  float* out = (float*)d_out;

  const size_t p_bytes  = (size_t)B_ * N_ * 256 * 2;  // 16 MB bf16 [U|V]
  const size_t wt_bytes = (size_t)256 * 128 * 2;      // 64 KB bf16 Wt

  if (ws_size >= p_bytes + wt_bytes) {
    unsigned short* P  = (unsigned short*)d_ws;
    unsigned short* Wt = (unsigned short*)((char*)d_ws + p_bytes);
    cvt_w_kernel<<<dim3(128), dim3(256), 0, stream>>>(W, Wt);
    gemm_kernel<<<dim3((B_ * N_) / 64), dim3(512), 0, stream>>>(x, Wt, P);
    gather_kernel<<<dim3(2048), dim3(256), 0, stream>>>(
        adj, P, x, bias, gamma, beta, out);
  } else {
    fused_f32_kernel<<<dim3((B_ * N_) / 64), dim3(512), 0, stream>>>(
        x, adj, W, bias, gamma, beta, out);
  }
}

// Round 13
// 108.300 us; speedup vs baseline: 1.0787x; 1.0008x over previous
//
#include <hip/hip_runtime.h>

#define B_ 4
#define N_ 8192
#define D_ 128
#define K_ 32

typedef short short8 __attribute__((ext_vector_type(8)));
typedef float f32x4 __attribute__((ext_vector_type(4)));

__device__ __forceinline__ unsigned short f2bf(float f) {
  unsigned int u = __float_as_uint(f);
  u += 0x7FFFu + ((u >> 16) & 1u);   // round-to-nearest-even
  return (unsigned short)(u >> 16);
}
__device__ __forceinline__ float bf2f(unsigned short h) {
  return __uint_as_float(((unsigned int)h) << 16);
}

// ---------- K0: Wt[col256][floc128] bf16, col256 = is_v*128 + d ------------
__global__ __launch_bounds__(256) void cvt_w_kernel(const float* __restrict__ W,
                                                    unsigned short* __restrict__ Wt) {
  int e = blockIdx.x * 256 + threadIdx.x;      // 32768 elements, coalesced read
  int d = e & 127, fglob = e >> 7;
  int is_v = fglob >> 7, floc = fglob & 127;
  Wt[(is_v * 128 + d) * 128 + floc] = f2bf(W[e]);
}

// ---------- K1: P[row][256] bf16 = [X*W1 | X*W2]  (M=64/block, 512 blocks) --
// Epilogue: acc -> swizzled LDS bf16 tile -> coalesced uint4 stores.
__global__ __launch_bounds__(512) void gemm_kernel(
    const float* __restrict__ x, const unsigned short* __restrict__ Wt,
    unsigned short* __restrict__ P) {
  __shared__ __align__(16) unsigned char in_tile[64 * 256];   // 16 KB staging
  __shared__ __align__(16) unsigned char out_tile[64 * 512];  // 32 KB epilogue

  const int t = threadIdx.x, wave = t >> 6, lane = t & 63;
  const int l15 = lane & 15, kg = lane >> 4;
  const long row0 = (long)blockIdx.x * 64;

  // stage 64x128 f32 -> bf16 LDS (byte ^= (row&7)<<4)
  #pragma unroll
  for (int i = 0; i < 4; ++i) {
    int idx = t + i * 512;                     // 2048 float4 chunks
    int row = idx >> 5, cs = idx & 31;
    float4 v = *reinterpret_cast<const float4*>(x + (row0 + row) * D_ + cs * 4);
    ushort4 o;
    o.x = f2bf(v.x); o.y = f2bf(v.y); o.z = f2bf(v.z); o.w = f2bf(v.w);
    *reinterpret_cast<ushort4*>(
        in_tile + ((row * 256 + cs * 8) ^ ((row & 7) << 4))) = o;
  }

  // B fragments from Wt: 2 coltiles x 4 k-steps, each one 16B load
  const int halfw = wave & 3, is_v = wave >> 2;
  short8 bw[2][4];
  #pragma unroll
  for (int tt = 0; tt < 2; ++tt) {
    const int col = is_v * 128 + halfw * 32 + tt * 16 + l15;
    #pragma unroll
    for (int ks = 0; ks < 4; ++ks)
      bw[tt][ks] = *reinterpret_cast<const short8*>(
          Wt + col * 128 + ks * 32 + kg * 8);
  }
  __syncthreads();

  f32x4 acc[4][2];
  #pragma unroll
  for (int r = 0; r < 4; ++r)
    #pragma unroll
    for (int tt = 0; tt < 2; ++tt)
      acc[r][tt] = (f32x4){0.f, 0.f, 0.f, 0.f};

  #pragma unroll
  for (int ks = 0; ks < 4; ++ks) {
    #pragma unroll
    for (int r = 0; r < 4; ++r) {
      int row = r * 16 + l15;
      short8 af = *reinterpret_cast<const short8*>(
          in_tile + ((row * 256 + ks * 64 + kg * 16) ^ ((row & 7) << 4)));
      acc[r][0] = __builtin_amdgcn_mfma_f32_16x16x32_bf16(af, bw[0][ks], acc[r][0], 0, 0, 0);
      acc[r][1] = __builtin_amdgcn_mfma_f32_16x16x32_bf16(af, bw[1][ks], acc[r][1], 0, 0, 0);
    }
  }

  // acc -> out_tile (bf16, swizzled byte ^= (row&7)<<4); disjoint from in_tile
  #pragma unroll
  for (int r = 0; r < 4; ++r)
    #pragma unroll
    for (int tt = 0; tt < 2; ++tt) {
      const int col = is_v * 128 + halfw * 32 + tt * 16 + l15;
      #pragma unroll
      for (int i = 0; i < 4; ++i) {
        int row = r * 16 + kg * 4 + i;
        *reinterpret_cast<unsigned short*>(
            out_tile + ((row * 512 + col * 2) ^ ((row & 7) << 4))) =
            f2bf(acc[r][tt][i]);
      }
    }
  __syncthreads();

  // coalesced 16B stores: 2048 uint4 chunks over 512 threads
  #pragma unroll
  for (int p = 0; p < 4; ++p) {
    int idx = t + p * 512;
    int row = idx >> 5, cb = (idx & 31) * 16;
    uint4 v = *reinterpret_cast<const uint4*>(
        out_tile + ((row * 512 + cb) ^ ((row & 7) << 4)));
    *reinterpret_cast<uint4*>(P + (row0 + row) * 256 + (cb >> 1)) = v;
  }
}

// ---------- K2: out[n] = LN(gelu(U[n] + mean_k V[adj[n,k]] + b) + x[n]) -----
// 2048 blocks x 256 thr; 2 nodes per wave in half-wave parallel, 2 j-iters.
// Gather: dwordx2/lane, 32 lanes cover a full 256B V row; one instruction
// serves both half-waves' rows. adj broadcast via shfl (ds_bpermute).
__global__ __launch_bounds__(256) void gather_kernel(
    const int* __restrict__ adj, const unsigned short* __restrict__ P,
    const float* __restrict__ x, const float* __restrict__ bias,
    const float* __restrict__ gamma, const float* __restrict__ beta,
    float* __restrict__ out) {
  const int t = threadIdx.x;
  const int wave = t >> 6, lane = t & 63;
  const int l31 = lane & 31, hs = lane & 32;
  // XCD swizzle (2048 = 8*256): each XCD gets a contiguous half-batch
  const int vblk = ((blockIdx.x & 7) << 8) + (blockIdx.x >> 3);
  const int nb0 = vblk * 16 + wave * 4;
  const int b = nb0 >> 13;
  const unsigned int* pd = (const unsigned int*)P;     // row stride 128 dwords
  const unsigned int* vb_dw = pd + (size_t)b * N_ * 128 + 64 + l31 * 2;
  const int c0 = l31 * 4;
  const float4 bi = *reinterpret_cast<const float4*>(bias + c0);
  const float4 ga = *reinterpret_cast<const float4*>(gamma + c0);
  const float4 be = *reinterpret_cast<const float4*>(beta + c0);

  #pragma unroll
  for (int j = 0; j < 2; ++j) {
    const int nb = nb0 + j * 2;                // halves handle nb, nb+1
    const int gn = nb + (lane >> 5);
    // adj rows for both nodes: 64 contiguous ints
    const int av = adj[(size_t)nb * K_ + lane];
    float a0 = 0.f, a1 = 0.f, a2 = 0.f, a3 = 0.f;
    #pragma unroll
    for (int k = 0; k < K_; ++k) {
      int rowk = __shfl(av, hs | k, 64);       // half-local broadcast
      ushort4 v = *reinterpret_cast<const ushort4*>(vb_dw + (size_t)rowk * 128);
      a0 += bf2f(v.x); a1 += bf2f(v.y); a2 += bf2f(v.z); a3 += bf2f(v.w);
    }
    const ushort4 ud = *reinterpret_cast<const ushort4*>(pd + (size_t)gn * 128 + l31 * 2);
    const float4 xv = *reinterpret_cast<const float4*>(x + (size_t)gn * D_ + c0);
    float h0 = bf2f(ud.x) + a0 * 0.03125f + bi.x;
    float h1 = bf2f(ud.y) + a1 * 0.03125f + bi.y;
    float h2 = bf2f(ud.z) + a2 * 0.03125f + bi.z;
    float h3 = bf2f(ud.w) + a3 * 0.03125f + bi.w;
    h0 = 0.5f * h0 * (1.f + erff(h0 * 0.70710678118f));
    h1 = 0.5f * h1 * (1.f + erff(h1 * 0.70710678118f));
    h2 = 0.5f * h2 * (1.f + erff(h2 * 0.70710678118f));
    h3 = 0.5f * h3 * (1.f + erff(h3 * 0.70710678118f));
    const float y0 = h0 + xv.x, y1 = h1 + xv.y;
    const float y2 = h2 + xv.z, y3 = h3 + xv.w;
    float s = y0 + y1 + y2 + y3;
    float sq = y0 * y0 + y1 * y1 + y2 * y2 + y3 * y3;
    #pragma unroll
    for (int off = 1; off < 32; off <<= 1) {   // reduce within 32-lane half
      s  += __shfl_xor(s, off, 64);
      sq += __shfl_xor(sq, off, 64);
    }
    const float mu   = s * (1.f / 128.f);
    const float rstd = rsqrtf(sq * (1.f / 128.f) - mu * mu + 1e-5f);
    float4 o;
    o.x = (y0 - mu) * rstd * ga.x + be.x;
    o.y = (y1 - mu) * rstd * ga.y + be.y;
    o.z = (y2 - mu) * rstd * ga.z + be.z;
    o.w = (y3 - mu) * rstd * ga.w + be.w;
    *reinterpret_cast<float4*>(out + (size_t)gn * D_ + c0) = o;
  }
}

// ---------------- fallback (no workspace): monolithic f32 path --------------
__global__ __launch_bounds__(512) void fused_f32_kernel(
    const float* __restrict__ x, const int* __restrict__ adj,
    const float* __restrict__ W, const float* __restrict__ bias,
    const float* __restrict__ gamma, const float* __restrict__ beta,
    float* __restrict__ out) {
  __shared__ __align__(16) unsigned char smem[40960];
  unsigned char* in_tile = smem;
  int* adj_lds = (int*)(smem + 32768);
  float* y = (float*)smem;
  const int t = threadIdx.x, wave = t >> 6, lane = t & 63;
  const int l15 = lane & 15, kg = lane >> 4;
  const int vid = (blockIdx.x & 7) * 64 + (blockIdx.x >> 3);
  const int bidx = vid >> 7;
  const long row0 = (long)bidx * N_ + (vid & 127) * 64;
  #pragma unroll
  for (int i = 0; i < 4; ++i)
    adj_lds[t + i * 512] = adj[row0 * K_ + t + i * 512];
  #pragma unroll
  for (int i = 0; i < 4; ++i) {
    int idx = t + i * 512;
    int row = idx >> 5, cp = (idx & 31) * 4;
    float4 v = *reinterpret_cast<const float4*>(x + (row0 + row) * D_ + cp);
    ushort4 o;
    o.x = f2bf(v.x); o.y = f2bf(v.y); o.z = f2bf(v.z); o.w = f2bf(v.w);
    *reinterpret_cast<ushort4*>(in_tile + row * 512 + ((2 * cp) ^ ((row & 7) << 4))) = o;
  }
  __syncthreads();
  {
    const int g = t & 31, rb = t >> 5, c0 = g * 4;
    #pragma unroll
    for (int batch = 0; batch < 4; ++batch) {
      int row = rb + batch * 16;
      const int* ap = adj_lds + row * K_;
      float a0 = 0, a1 = 0, a2 = 0, a3 = 0;
      for (int k = 0; k < K_; ++k) {
        float4 v = *reinterpret_cast<const float4*>(x + ((long)bidx * N_ + ap[k]) * D_ + c0);
        a0 += v.x; a1 += v.y; a2 += v.z; a3 += v.w;
      }
      ushort4 m;
      m.x = f2bf(a0 * 0.03125f); m.y = f2bf(a1 * 0.03125f);
      m.z = f2bf(a2 * 0.03125f); m.w = f2bf(a3 * 0.03125f);
      *reinterpret_cast<ushort4*>(in_tile + row * 512 +
                                  ((2 * (D_ + c0)) ^ ((row & 7) << 4))) = m;
    }
  }
  __syncthreads();
  const int dl = (wave << 4) + l15;
  f32x4 acc[4];
  #pragma unroll
  for (int r = 0; r < 4; ++r) acc[r] = (f32x4){0.f, 0.f, 0.f, 0.f};
  #pragma unroll
  for (int ks = 0; ks < 8; ++ks) {
    short8 bwk;
    #pragma unroll
    for (int j = 0; j < 8; ++j)
      bwk[j] = (short)f2bf(W[(ks * 32 + kg * 8 + j) * D_ + dl]);
    #pragma unroll
    for (int r = 0; r < 4; ++r) {
      int row = r * 16 + l15;
      short8 af = *reinterpret_cast<const short8*>(
          in_tile + row * 512 + ((2 * (ks * 32 + kg * 8)) ^ ((row & 7) << 4)));
      acc[r] = __builtin_amdgcn_mfma_f32_16x16x32_bf16(af, bwk, acc[r], 0, 0, 0);
    }
  }
  __syncthreads();
  const float bv = bias[dl];
  #pragma unroll
  for (int r = 0; r < 4; ++r)
    #pragma unroll
    for (int i = 0; i < 4; ++i) {
      int row = r * 16 + kg * 4 + i;
      float h = acc[r][i] + bv;
      float ge = 0.5f * h * (1.f + erff(h * 0.70710678118f));
      y[row * 132 + dl] = ge + x[(row0 + row) * D_ + dl];
    }
  __syncthreads();
  {
    const int row = t >> 3, l8 = t & 7;
    const float* yr = y + row * 132 + l8 * 16;
    float4 v[4];
    float s = 0.f, sq = 0.f;
    #pragma unroll
    for (int i = 0; i < 4; ++i) {
      v[i] = *reinterpret_cast<const float4*>(yr + i * 4);
      s += v[i].x + v[i].y + v[i].z + v[i].w;
      sq += v[i].x * v[i].x + v[i].y * v[i].y + v[i].z * v[i].z + v[i].w * v[i].w;
    }
    #pragma unroll
    for (int off = 1; off < 8; off <<= 1) {
      s += __shfl_xor(s, off, 64);
      sq += __shfl_xor(sq, off, 64);
    }
    const float mu = s * (1.f / 128.f);
    const float rstd = rsqrtf(sq * (1.f / 128.f) - mu * mu + 1e-5f);
    float* orow = out + (row0 + row) * D_ + l8 * 16;
    #pragma unroll
    for (int i = 0; i < 4; ++i) {
      float4 g = *reinterpret_cast<const float4*>(gamma + l8 * 16 + i * 4);
      float4 bb = *reinterpret_cast<const float4*>(beta + l8 * 16 + i * 4);
      float4 o;
      o.x = (v[i].x - mu) * rstd * g.x + bb.x;
      o.y = (v[i].y - mu) * rstd * g.y + bb.y;
      o.z = (v[i].z - mu) * rstd * g.z + bb.z;
      o.w = (v[i].w - mu) * rstd * g.w + bb.w;
      *reinterpret_cast<float4*>(orow + i * 4) = o;
    }
  }
}

extern "C" void kernel_launch(void* const* d_in, const int* in_sizes, int n_in,
                              void* d_out, int out_size, void* d_ws, size_t ws_size,
                              hipStream_t stream) {
  const float* x     = (const float*)d_in[0];
  const int*   adj   = (const int*)d_in[1];
  const float* W     = (const float*)d_in[2];
  const float* bias  = (const float*)d_in[3];
  const float* gamma = (const float*)d_in[4];
  const float* beta  = (const float*)d_in[5];
  float* out = (float*)d_out;

  const size_t p_bytes  = (size_t)B_ * N_ * 256 * 2;  // 16 MB bf16 [U|V]
  const size_t wt_bytes = (size_t)256 * 128 * 2;      // 64 KB bf16 Wt

  if (ws_size >= p_bytes + wt_bytes) {
    unsigned short* P  = (unsigned short*)d_ws;
    unsigned short* Wt = (unsigned short*)((char*)d_ws + p_bytes);
    cvt_w_kernel<<<dim3(128), dim3(256), 0, stream>>>(W, Wt);
    gemm_kernel<<<dim3((B_ * N_) / 64), dim3(512), 0, stream>>>(x, Wt, P);
    gather_kernel<<<dim3(2048), dim3(256), 0, stream>>>(
        adj, P, x, bias, gamma, beta, out);
  } else {
    fused_f32_kernel<<<dim3((B_ * N_) / 64), dim3(512), 0, stream>>>(
        x, adj, W, bias, gamma, beta, out);
  }
}